// Round 1
// 718.574 us; speedup vs baseline: 1.0772x; 1.0772x over previous
//
#include <hip/hip_runtime.h>
#include <hip/hip_bf16.h>

typedef unsigned short u16;
typedef __bf16 bf16x8 __attribute__((ext_vector_type(8)));
typedef float f32x4 __attribute__((ext_vector_type(4)));

// ---------- helpers ----------

__device__ __forceinline__ u16 f32_to_bf16(float f) {
    unsigned int u = __float_as_uint(f);
    unsigned int r = (u + 0x7FFFu + ((u >> 16) & 1u)) >> 16;  // RNE
    return (u16)r;
}

__device__ __forceinline__ unsigned pack2(float a, float b) {
    return (unsigned)f32_to_bf16(a) | ((unsigned)f32_to_bf16(b) << 16);
}

__device__ __forceinline__ void load_lds16(const void* g, void* s) {
    __builtin_amdgcn_global_load_lds(
        (__attribute__((address_space(1))) void*)g,
        (__attribute__((address_space(3))) void*)s,
        16, 0, 0);
}

// ---------- kernel 1: x fp32 -> bf16 (8 elems/thread, 16B stores) ----------

__global__ __launch_bounds__(256) void convert_f32_bf16(
        const float* __restrict__ in, u16* __restrict__ out) {
    int i = blockIdx.x * 256 + threadIdx.x;            // grid exactly n/8
    const float4* in4 = (const float4*)in;
    float4 v0 = in4[(size_t)i * 2];
    float4 v1 = in4[(size_t)i * 2 + 1];
    uint4 r;
    r.x = pack2(v0.x, v0.y);
    r.y = pack2(v0.z, v0.w);
    r.z = pack2(v1.x, v1.y);
    r.w = pack2(v1.z, v1.w);
    ((uint4*)out)[i] = r;
}

// ---------- kernel 2: dequant indices -> y_bf (8 elems/thread) ----------

__global__ __launch_bounds__(256) void dequant_kernel(
        const int* __restrict__ idx, const float* __restrict__ cent,
        u16* __restrict__ out) {
    __shared__ float lut[16];
    if (threadIdx.x < 16) lut[threadIdx.x] = cent[threadIdx.x];
    __syncthreads();
    int i = blockIdx.x * 256 + threadIdx.x;
    const int4* in4 = (const int4*)idx;
    int4 a = in4[(size_t)i * 2];
    int4 b = in4[(size_t)i * 2 + 1];
    uint4 r;
    r.x = pack2(lut[a.x], lut[a.y]);
    r.y = pack2(lut[a.z], lut[a.w]);
    r.z = pack2(lut[b.x], lut[b.y]);
    r.w = pack2(lut[b.z], lut[b.w]);
    ((uint4*)out)[i] = r;
}

// ---------- kernel 3: Pi (4096x4096 fp32) -> Pi^T bf16 ----------

__global__ __launch_bounds__(256) void transpose_to_bf16(
        const float* __restrict__ Pi, u16* __restrict__ PiT) {
    __shared__ float tile[32][33];
    const int tx = threadIdx.x;      // 0..31
    const int ty = threadIdx.y;      // 0..7
    const int j0 = blockIdx.x * 32;  // Pi column block
    const int k0 = blockIdx.y * 32;  // Pi row block
#pragma unroll
    for (int i = 0; i < 4; i++)
        tile[ty + 8 * i][tx] = Pi[(size_t)(k0 + ty + 8 * i) * 4096 + j0 + tx];
    __syncthreads();
#pragma unroll
    for (int i = 0; i < 4; i++)
        PiT[(size_t)(j0 + ty + 8 * i) * 4096 + k0 + tx] =
            f32_to_bf16(tile[tx][ty + 8 * i]);
}

// ---------- GEMM: C[m][n] = sum_k A[m][k] * B[n][k]  (B stored N x K) ----------
// 256x256 block tile, BK=64, 8 waves (2Mx4N), 512 threads.
// 8-phase schedule (m201 template): per phase {ds_read subtile || 1 half-tile
// global_load_lds prefetch -> s_barrier -> lgkmcnt(0)+sched_barrier ->
// setprio(1) + 16x mfma_f32_16x16x32_bf16 + setprio(0) -> s_barrier}.
// LDS = ring of 8 half-tile slots (A/B x k-half x dbuf), 256x32 bf16 each
// = 128 KiB. Counted vmcnt(6) at half-K-tile boundaries; never 0 in the
// main loop (drain 6->4->0 across the two peeled tail tiles).
// Lookahead L=5 half-tiles: stage of slot h issues >=2 barriers after the
// last ds_read of its previous occupant h-8 (hand-verified ring schedule).
//
// LDS XOR swizzle: 8-elem chunk c of row r stored at c ^ ((r>>1)&3) --
// applied by permuting the *global* source chunk (LDS dest linear, m104)
// and by the same XOR on the ds_read address. The 16-row x 4-chunk MFMA
// fragment read then covers 8 distinct 16B bank groups per 8 lanes.
//
// MODE 0: store bf16, scale by aux[row]   (W = (yhat@Pi) * row_norms)
// MODE 1: store fp32, add aux[col]        (out = x@W^T + bias)

template <int MODE>
__global__ __launch_bounds__(512, 2) void gemm_bt(
        const u16* __restrict__ A, const u16* __restrict__ Bm,
        const float* __restrict__ aux, float* __restrict__ Cf,
        u16* __restrict__ Cb, int M, int N, int K) {
    __shared__ u16 As[4 * 8192];   // slots: [buf][khalf] 256x32 bf16
    __shared__ u16 Bs[4 * 8192];

    const int tid  = threadIdx.x;
    const int lane = tid & 63;
    const int wv   = tid >> 6;
    const int wr   = wv >> 2;        // 0..1  m-half (128 rows)
    const int wc   = wv & 3;         // 0..3  n-quarter (64 cols)

    // XCD-aware bijective swizzle (nwg % 8 == 0 for both launches; gridDim.x==16)
    const int nwg  = gridDim.x * gridDim.y;
    const int orig = blockIdx.y * gridDim.x + blockIdx.x;
    const int swz  = (orig & 7) * (nwg >> 3) + (orig >> 3);
    const int m0   = (swz >> 4) << 8;
    const int n0   = (swz & 15) << 8;

    // ---- staging: thread -> (row sr + 128*l, chunk tid&3) of a 256x32 slot;
    //      source chunk pre-swizzled, LDS dest lane-contiguous.
    const int sr  = tid >> 2;
    const int csw = ((tid & 3) ^ ((tid >> 3) & 3)) << 3;
    const u16* a0 = A  + (size_t)(m0 + sr) * K + csw;
    const u16* a1 = A  + (size_t)(m0 + 128 + sr) * K + csw;
    const u16* b0 = Bm + (size_t)(n0 + sr) * K + csw;
    const u16* b1 = Bm + (size_t)(n0 + 128 + sr) * K + csw;
    u16* dA = As + tid * 8;
    u16* dB = Bs + tid * 8;

    // ---- fragment read offsets (swizzled to match staging; loop-invariant)
    const int l15   = lane & 15;
    const int ck    = (((lane >> 4) ^ ((lane >> 1) & 3)) << 3);
    const int laneA = (wr * 128 + l15) * 32 + ck;
    const int laneB = (wc * 64 + l15) * 32 + ck;

    f32x4 acc[8][4];
#pragma unroll
    for (int i = 0; i < 8; i++)
#pragma unroll
        for (int j = 0; j < 4; j++) acc[i][j] = (f32x4){0.f, 0.f, 0.f, 0.f};
    bf16x8 bF[4];   // B frags held across the j0->j1 / j2->j3 phase pairs

#define STAGE_A(SLOT, COL) do { \
        load_lds16(a0 + (COL), dA + (SLOT) * 8192); \
        load_lds16(a1 + (COL), dA + (SLOT) * 8192 + 4096); } while (0)
#define STAGE_B(SLOT, COL) do { \
        load_lds16(b0 + (COL), dB + (SLOT) * 8192); \
        load_lds16(b1 + (COL), dB + (SLOT) * 8192 + 4096); } while (0)
#define VM(N) asm volatile("s_waitcnt vmcnt(" #N ")" ::: "memory")

#define PHASE(SB, MH, RB, STAGE, WAIT) do { \
        bf16x8 aF[4]; \
        _Pragma("unroll") \
        for (int i_ = 0; i_ < 4; i_++) \
            aF[i_] = *(const bf16x8*)&As[(SB) + laneA + ((MH) * 4 + i_) * 512]; \
        if (RB) { \
            _Pragma("unroll") \
            for (int i_ = 0; i_ < 4; i_++) \
                bF[i_] = *(const bf16x8*)&Bs[(SB) + laneB + i_ * 512]; \
        } \
        STAGE; \
        WAIT; \
        __builtin_amdgcn_s_barrier(); \
        asm volatile("s_waitcnt lgkmcnt(0)" ::: "memory"); \
        __builtin_amdgcn_sched_barrier(0); \
        __builtin_amdgcn_s_setprio(1); \
        _Pragma("unroll") \
        for (int i_ = 0; i_ < 4; i_++) { \
            _Pragma("unroll") \
            for (int n_ = 0; n_ < 4; n_++) \
                acc[(MH) * 4 + i_][n_] = __builtin_amdgcn_mfma_f32_16x16x32_bf16( \
                    aF[i_], bF[n_], acc[(MH) * 4 + i_][n_], 0, 0, 0); \
        } \
        __builtin_amdgcn_s_setprio(0); \
        __builtin_amdgcn_s_barrier(); \
    } while (0)

    const int NT = K >> 6;   // K-tiles (64 for K=4096; even, >= 4)

    // ---- prologue: half-tiles h0..h4 (A-k0/B-k0/A-k1/B-k1 of t0, A-k0 of t1)
    STAGE_A(0, 0);
    STAGE_B(0, 0);
    STAGE_A(1, 32);
    STAGE_B(1, 32);
    STAGE_A(2, 64);
    VM(6);                       // h0,h1 (first 4 loads) complete
    __builtin_amdgcn_s_barrier();

    // ---- main loop: 2 K-tiles / iteration, tiles 0..NT-3
#pragma unroll 1
    for (int t = 0; t < NT - 2; t += 2) {
        const int c1 = (t + 1) * 64;
        const int c2 = c1 + 64;
        // tile t (buf0: slots 0,1)
        PHASE(0,     0, 1, STAGE_B(2, c1),      ((void)0));
        PHASE(0,     1, 0, STAGE_A(3, c1 + 32), VM(6));
        PHASE(8192,  0, 1, STAGE_B(3, c1 + 32), ((void)0));
        PHASE(8192,  1, 0, STAGE_A(0, c2),      VM(6));
        // tile t+1 (buf1: slots 2,3)
        PHASE(16384, 0, 1, STAGE_B(0, c2),      ((void)0));
        PHASE(16384, 1, 0, STAGE_A(1, c2 + 32), VM(6));
        PHASE(24576, 0, 1, STAGE_B(1, c2 + 32), ((void)0));
        PHASE(24576, 1, 0, STAGE_A(2, c2 + 64), VM(6));
    }

    // ---- tail tile NT-2 (buf0): stage last parts of tile NT-1, drain to 4
    {
        const int cT = (NT - 1) * 64;
        PHASE(0,    0, 1, STAGE_B(2, cT),      ((void)0));
        PHASE(0,    1, 0, STAGE_A(3, cT + 32), VM(6));
        PHASE(8192, 0, 1, STAGE_B(3, cT + 32), ((void)0));
        PHASE(8192, 1, 0, ((void)0),           VM(4));
    }
    // ---- tail tile NT-1 (buf1): no stages, drain to 0 before its k1 phases
    {
        PHASE(16384, 0, 1, ((void)0), ((void)0));
        PHASE(16384, 1, 0, ((void)0), VM(0));
        PHASE(24576, 0, 1, ((void)0), ((void)0));
        PHASE(24576, 1, 0, ((void)0), ((void)0));
    }

#undef PHASE
#undef VM
#undef STAGE_B
#undef STAGE_A

    // ---- epilogue — 16x16 C/D: col = lane&15, row = (lane>>4)*4 + reg
    const int colf = l15;
    const int r0   = (lane >> 4) << 2;
#pragma unroll
    for (int m = 0; m < 8; m++) {
        const int row = m0 + wr * 128 + m * 16 + r0;
#pragma unroll
        for (int n = 0; n < 4; n++) {
            const int col = n0 + wc * 64 + n * 16 + colf;
            if (MODE == 0) {
#pragma unroll
                for (int e = 0; e < 4; e++)
                    Cb[(size_t)(row + e) * N + col] =
                        f32_to_bf16(acc[m][n][e] * aux[row + e]);
            } else {
                const float bv = aux[col];
#pragma unroll
                for (int e = 0; e < 4; e++)
                    Cf[(size_t)(row + e) * N + col] = acc[m][n][e] + bv;
            }
        }
    }
}

// ---------- launch ----------

extern "C" void kernel_launch(void* const* d_in, const int* in_sizes, int n_in,
                              void* d_out, int out_size, void* d_ws, size_t ws_size,
                              hipStream_t stream) {
    const float* x         = (const float*)d_in[0];   // (4,2048,4096) fp32
    const int*   indices   = (const int*)d_in[1];     // (4096,4096) int32
    const float* centroids = (const float*)d_in[2];   // (16,) fp32
    const float* Pi        = (const float*)d_in[3];   // (4096,4096) fp32
    const float* row_norms = (const float*)d_in[4];   // (4096,) fp32
    const float* bias      = (const float*)d_in[5];   // (4096,) fp32
    float* out = (float*)d_out;                       // (4,2048,4096) fp32

    // workspace layout (bf16 as u16): total 160 MiB
    u16* x_bf = (u16*)d_ws;                 // 8192*4096
    u16* y_bf = x_bf + (size_t)33554432;    // 4096*4096
    u16* pi_t = y_bf + (size_t)16777216;    // 4096*4096 (Pi transposed)
    u16* w_bf = pi_t + (size_t)16777216;    // 4096*4096

    convert_f32_bf16<<<16384, 256, 0, stream>>>(x, x_bf);
    dequant_kernel<<<8192, 256, 0, stream>>>(indices, centroids, y_bf);
    transpose_to_bf16<<<dim3(128, 128), dim3(32, 8), 0, stream>>>(Pi, pi_t);
    // W = (yhat @ Pi) * row_norms : A=y_bf (4096xK), B=pi_t (4096xK)
    gemm_bt<0><<<dim3(16, 16), 512, 0, stream>>>(
        y_bf, pi_t, row_norms, nullptr, w_bf, 4096, 4096, 4096);
    // out = x @ W^T + bias : A=x_bf (8192xK), B=w_bf (4096xK)
    gemm_bt<1><<<dim3(16, 32), 512, 0, stream>>>(
        x_bf, w_bf, bias, out, nullptr, 8192, 4096, 4096);
}

// Round 2
// 677.698 us; speedup vs baseline: 1.1422x; 1.0603x over previous
//
#include <hip/hip_runtime.h>
#include <hip/hip_bf16.h>

typedef unsigned short u16;
typedef __bf16 bf16x8 __attribute__((ext_vector_type(8)));
typedef float f32x4 __attribute__((ext_vector_type(4)));

// ---------- helpers ----------

__device__ __forceinline__ u16 f32_to_bf16(float f) {
    unsigned int u = __float_as_uint(f);
    unsigned int r = (u + 0x7FFFu + ((u >> 16) & 1u)) >> 16;  // RNE
    return (u16)r;
}

__device__ __forceinline__ unsigned pack2(float a, float b) {
    return (unsigned)f32_to_bf16(a) | ((unsigned)f32_to_bf16(b) << 16);
}

__device__ __forceinline__ void load_lds16(const void* g, void* s) {
    __builtin_amdgcn_global_load_lds(
        (__attribute__((address_space(1))) void*)g,
        (__attribute__((address_space(3))) void*)s,
        16, 0, 0);
}

// ---------- kernel 1: x fp32 -> bf16 (8 elems/thread, 16B stores) ----------

__global__ __launch_bounds__(256) void convert_f32_bf16(
        const float* __restrict__ in, u16* __restrict__ out) {
    int i = blockIdx.x * 256 + threadIdx.x;            // grid exactly n/8
    const float4* in4 = (const float4*)in;
    float4 v0 = in4[(size_t)i * 2];
    float4 v1 = in4[(size_t)i * 2 + 1];
    uint4 r;
    r.x = pack2(v0.x, v0.y);
    r.y = pack2(v0.z, v0.w);
    r.z = pack2(v1.x, v1.y);
    r.w = pack2(v1.z, v1.w);
    ((uint4*)out)[i] = r;
}

// ---------- kernel 2: dequant indices -> y_bf (8 elems/thread) ----------

__global__ __launch_bounds__(256) void dequant_kernel(
        const int* __restrict__ idx, const float* __restrict__ cent,
        u16* __restrict__ out) {
    __shared__ float lut[16];
    if (threadIdx.x < 16) lut[threadIdx.x] = cent[threadIdx.x];
    __syncthreads();
    int i = blockIdx.x * 256 + threadIdx.x;
    const int4* in4 = (const int4*)idx;
    int4 a = in4[(size_t)i * 2];
    int4 b = in4[(size_t)i * 2 + 1];
    uint4 r;
    r.x = pack2(lut[a.x], lut[a.y]);
    r.y = pack2(lut[a.z], lut[a.w]);
    r.z = pack2(lut[b.x], lut[b.y]);
    r.w = pack2(lut[b.z], lut[b.w]);
    ((uint4*)out)[i] = r;
}

// ---------- kernel 3: Pi (4096x4096 fp32) -> Pi^T bf16 ----------

__global__ __launch_bounds__(256) void transpose_to_bf16(
        const float* __restrict__ Pi, u16* __restrict__ PiT) {
    __shared__ float tile[32][33];
    const int tx = threadIdx.x;      // 0..31
    const int ty = threadIdx.y;      // 0..7
    const int j0 = blockIdx.x * 32;  // Pi column block
    const int k0 = blockIdx.y * 32;  // Pi row block
#pragma unroll
    for (int i = 0; i < 4; i++)
        tile[ty + 8 * i][tx] = Pi[(size_t)(k0 + ty + 8 * i) * 4096 + j0 + tx];
    __syncthreads();
#pragma unroll
    for (int i = 0; i < 4; i++)
        PiT[(size_t)(j0 + ty + 8 * i) * 4096 + k0 + tx] =
            f32_to_bf16(tile[tx][ty + 8 * i]);
}

// ---------- GEMM: C[m][n] = sum_k A[m][k] * B[n][k]  (B stored N x K) ----------
// 256x256 block tile, BK=64, 8 waves (2Mx4N), 512 threads, 128 KiB LDS
// (ring of 8 half-tile slots: {A,B} x {k0,k1} x dbuf, 256x32 bf16 each).
//
// Software-pipelined 8-phase schedule, ONE barrier per phase:
//   barrier -> lgkmcnt(0) -> stage 1 half-tile (2 global_load_lds) ->
//   setprio(1) + 16 MFMA on frags read LAST section + setprio(0) ->
//   issue ds_reads for NEXT phase -> [odd sections] vmcnt(6).
// The ds_reads drain during the following MFMA section (~620 cyc >> LDS
// need), so lgkmcnt(0) is ~free; barriers halve vs the 2-barrier phase.
// Ring schedule (hand-verified):
//   - restage of a slot is >=1 barrier after the lgkmcnt(0) that retires
//     the previous occupant's reads (stage order p1..p8 =
//     A(t+1,k1),B(t+1,k1),A(t+2,k0),B(t+2,k0),A(t+2,k1),B(t+2,k1),
//     A(t+3,k0),B(t+3,k0));
//   - VM(6) at p1/p3/p5/p7 publishes exactly the two half-tiles read two
//     sections later; 3-section HBM lookahead (~2000 cyc > 900 miss lat).
// Tail: loop fully uniform; out-of-range stage columns clamp to 0 (dummy
// data into already-retired slots, never read).
//
// LDS XOR swizzle: 8-elem chunk c of row r stored at c ^ ((r>>1)&3) --
// global source permuted (LDS dest linear), same XOR on ds_read address.
//
// MODE 0: store bf16, scale by aux[row]   (W = (yhat@Pi) * row_norms)
// MODE 1: store fp32, add aux[col]        (out = x@W^T + bias)

template <int MODE>
__global__ __launch_bounds__(512, 2) void gemm_bt(
        const u16* __restrict__ A, const u16* __restrict__ Bm,
        const float* __restrict__ aux, float* __restrict__ Cf,
        u16* __restrict__ Cb, int M, int N, int K) {
    __shared__ u16 As[4 * 8192];   // slots: [buf][khalf] 256x32 bf16
    __shared__ u16 Bs[4 * 8192];

    const int tid  = threadIdx.x;
    const int lane = tid & 63;
    const int wv   = tid >> 6;
    const int wr   = wv >> 2;        // 0..1  m-half (128 rows)
    const int wc   = wv & 3;         // 0..3  n-quarter (64 cols)

    // XCD-aware bijective swizzle (nwg % 8 == 0 for both launches)
    const int nwg  = gridDim.x * gridDim.y;
    const int orig = blockIdx.y * gridDim.x + blockIdx.x;
    const int swz  = (orig & 7) * (nwg >> 3) + (orig >> 3);
    const int m0   = (swz >> 4) << 8;
    const int n0   = (swz & 15) << 8;

    // ---- staging: thread -> (row sr + 128*l, chunk tid&3) of a 256x32 slot;
    //      source chunk pre-swizzled, LDS dest lane-contiguous.
    const int sr  = tid >> 2;
    const int csw = ((tid & 3) ^ ((tid >> 3) & 3)) << 3;
    const u16* a0 = A  + (size_t)(m0 + sr) * K + csw;
    const u16* a1 = A  + (size_t)(m0 + 128 + sr) * K + csw;
    const u16* b0 = Bm + (size_t)(n0 + sr) * K + csw;
    const u16* b1 = Bm + (size_t)(n0 + 128 + sr) * K + csw;
    u16* dA = As + tid * 8;
    u16* dB = Bs + tid * 8;

    // ---- fragment read offsets (swizzled to match staging; loop-invariant)
    const int l15   = lane & 15;
    const int ck    = (((lane >> 4) ^ ((lane >> 1) & 3)) << 3);
    const int laneA = (wr * 128 + l15) * 32 + ck;
    const int laneB = (wc * 64 + l15) * 32 + ck;

    f32x4 acc[8][4];
#pragma unroll
    for (int i = 0; i < 8; i++)
#pragma unroll
        for (int j = 0; j < 4; j++) acc[i][j] = (f32x4){0.f, 0.f, 0.f, 0.f};
    bf16x8 aF[4], bF[4];

#define STAGE_A(SLOT, COL) do { \
        load_lds16(a0 + (COL), dA + (SLOT) * 8192); \
        load_lds16(a1 + (COL), dA + (SLOT) * 8192 + 4096); } while (0)
#define STAGE_B(SLOT, COL) do { \
        load_lds16(b0 + (COL), dB + (SLOT) * 8192); \
        load_lds16(b1 + (COL), dB + (SLOT) * 8192 + 4096); } while (0)
#define VMW(N) asm volatile("s_waitcnt vmcnt(" #N ")" ::: "memory")

// One pipeline section: MFMA phase (MHC = its m-half) consuming frags read
// in the PREVIOUS section; stage one half-tile; read frags for NEXT phase
// (RSB slot base, RMH m-half, RDB = also refresh B frags); optional vmcnt.
#define SECTION(MHC, STG, RSB, RMH, RDB, VMS) do { \
        __builtin_amdgcn_s_barrier(); \
        asm volatile("s_waitcnt lgkmcnt(0)" ::: "memory"); \
        STG; \
        __builtin_amdgcn_s_setprio(1); \
        _Pragma("unroll") \
        for (int i_ = 0; i_ < 4; i_++) { \
            _Pragma("unroll") \
            for (int n_ = 0; n_ < 4; n_++) \
                acc[(MHC) * 4 + i_][n_] = __builtin_amdgcn_mfma_f32_16x16x32_bf16( \
                    aF[i_], bF[n_], acc[(MHC) * 4 + i_][n_], 0, 0, 0); \
        } \
        __builtin_amdgcn_s_setprio(0); \
        _Pragma("unroll") \
        for (int i_ = 0; i_ < 4; i_++) \
            aF[i_] = *(const bf16x8*)&As[(RSB) + laneA + ((RMH) * 4 + i_) * 512]; \
        if (RDB) { \
            _Pragma("unroll") \
            for (int i_ = 0; i_ < 4; i_++) \
                bF[i_] = *(const bf16x8*)&Bs[(RSB) + laneB + i_ * 512]; \
        } \
        VMS; \
    } while (0)

    const int NT = K >> 6;   // K-tiles (64 for K=4096; even, >= 4)

    // ---- prologue: stage h0..h5 = {A,B}(0,k0),{A,B}(0,k1),{A,B}(1,k0)
    STAGE_A(0, 0);  STAGE_B(0, 0);
    STAGE_A(1, 32); STAGE_B(1, 32);
    STAGE_A(2, 64); STAGE_B(2, 64);
    VMW(8);                      // h0,h1 complete (12 issued, 4 oldest done)
    __builtin_amdgcn_s_barrier();
    // frags for phase 1 (tile 0, k0, MH0)
#pragma unroll
    for (int i_ = 0; i_ < 4; i_++)
        aF[i_] = *(const bf16x8*)&As[laneA + i_ * 512];
#pragma unroll
    for (int i_ = 0; i_ < 4; i_++)
        bF[i_] = *(const bf16x8*)&Bs[laneB + i_ * 512];

    // ---- main loop: fully uniform, 2 K-tiles (8 sections) / iteration
#pragma unroll 1
    for (int t = 0; t < NT; t += 2) {
        const int cB1 = (t + 1) * 64 + 32;                  // always valid
        const int c2  = (t + 2 < NT) ? (t + 2) * 64 : 0;    // clamped tail
        const int c3  = (t + 3 < NT) ? (t + 3) * 64 : 0;    // clamped tail
        SECTION(0, STAGE_A(3, cB1),     0,     1, 0, VMW(6));
        SECTION(1, STAGE_B(3, cB1),     8192,  0, 1, (void)0);
        SECTION(0, STAGE_A(0, c2),      8192,  1, 0, VMW(6));
        SECTION(1, STAGE_B(0, c2),      16384, 0, 1, (void)0);
        SECTION(0, STAGE_A(1, c2 + 32), 16384, 1, 0, VMW(6));
        SECTION(1, STAGE_B(1, c2 + 32), 24576, 0, 1, (void)0);
        SECTION(0, STAGE_A(2, c3),      24576, 1, 0, VMW(6));
        SECTION(1, STAGE_B(2, c3),      0,     0, 1, (void)0);
    }

#undef SECTION
#undef VMW
#undef STAGE_B
#undef STAGE_A

    // ---- epilogue — 16x16 C/D: col = lane&15, row = (lane>>4)*4 + reg
    const int colf = l15;
    const int r0   = (lane >> 4) << 2;
#pragma unroll
    for (int m = 0; m < 8; m++) {
        const int row = m0 + wr * 128 + m * 16 + r0;
#pragma unroll
        for (int n = 0; n < 4; n++) {
            const int col = n0 + wc * 64 + n * 16 + colf;
            if (MODE == 0) {
#pragma unroll
                for (int e = 0; e < 4; e++)
                    Cb[(size_t)(row + e) * N + col] =
                        f32_to_bf16(acc[m][n][e] * aux[row + e]);
            } else {
                const float bv = aux[col];
#pragma unroll
                for (int e = 0; e < 4; e++)
                    Cf[(size_t)(row + e) * N + col] = acc[m][n][e] + bv;
            }
        }
    }
}

// ---------- launch ----------

extern "C" void kernel_launch(void* const* d_in, const int* in_sizes, int n_in,
                              void* d_out, int out_size, void* d_ws, size_t ws_size,
                              hipStream_t stream) {
    const float* x         = (const float*)d_in[0];   // (4,2048,4096) fp32
    const int*   indices   = (const int*)d_in[1];     // (4096,4096) int32
    const float* centroids = (const float*)d_in[2];   // (16,) fp32
    const float* Pi        = (const float*)d_in[3];   // (4096,4096) fp32
    const float* row_norms = (const float*)d_in[4];   // (4096,) fp32
    const float* bias      = (const float*)d_in[5];   // (4096,) fp32
    float* out = (float*)d_out;                       // (4,2048,4096) fp32

    // workspace layout (bf16 as u16): total 160 MiB
    u16* x_bf = (u16*)d_ws;                 // 8192*4096
    u16* y_bf = x_bf + (size_t)33554432;    // 4096*4096
    u16* pi_t = y_bf + (size_t)16777216;    // 4096*4096 (Pi transposed)
    u16* w_bf = pi_t + (size_t)16777216;    // 4096*4096

    convert_f32_bf16<<<16384, 256, 0, stream>>>(x, x_bf);
    dequant_kernel<<<8192, 256, 0, stream>>>(indices, centroids, y_bf);
    transpose_to_bf16<<<dim3(128, 128), dim3(32, 8), 0, stream>>>(Pi, pi_t);
    // W = (yhat @ Pi) * row_norms : A=y_bf (4096xK), B=pi_t (4096xK)
    gemm_bt<0><<<dim3(16, 16), 512, 0, stream>>>(
        y_bf, pi_t, row_norms, nullptr, w_bf, 4096, 4096, 4096);
    // out = x @ W^T + bias : A=x_bf (8192xK), B=w_bf (4096xK)
    gemm_bt<1><<<dim3(16, 32), 512, 0, stream>>>(
        x_bf, w_bf, bias, out, nullptr, 8192, 4096, 4096);
}